// Round 1
// baseline (3841.978 us; speedup 1.0000x reference)
//
#include <hip/hip_runtime.h>
#include <hip/hip_bf16.h>

static constexpr float NEG_SLOPE = 0.2f;
static constexpr float LN_EPS = 1e-5f;

// ---- monotone float<->uint mapping for atomicMax on floats ----
__device__ __forceinline__ unsigned ford(float x) {
  unsigned u = __float_as_uint(x);
  return (u & 0x80000000u) ? ~u : (u | 0x80000000u);
}
__device__ __forceinline__ float funord(unsigned v) {
  return (v & 0x80000000u) ? __uint_as_float(v & 0x7fffffffu)
                           : __uint_as_float(~v);
}

// ---- K1: xl = x@Wl + bl ; xr = x@Wr + br  (fused, 32 rows/block) ----
// 256 threads = 128 cols x {Wl, Wr}. X tile transposed in LDS so the inner
// loop reads X via broadcast (same addr all lanes) and W from L2 (coalesced,
// fully reused across blocks).
__global__ __launch_bounds__(256) void k_gemm_xlxr(
    const float* __restrict__ x, const float* __restrict__ Wl,
    const float* __restrict__ bl, const float* __restrict__ Wr,
    const float* __restrict__ br, float* __restrict__ xl,
    float* __restrict__ xr, int n)
{
  __shared__ float Xt[128 * 34];  // [k][r], stride 34 avoids bank conflicts
  const int t = threadIdx.x;
  const int col = t & 127;
  const bool isR = t >= 128;
  const float* __restrict__ W = isR ? Wr : Wl;
  float* __restrict__ outp = isR ? xr : xl;
  const float bia = isR ? br[col] : bl[col];
  const int row0 = blockIdx.x * 32;
  const int nr = min(32, n - row0);
  for (int i = t; i < 32 * 128; i += 256) {
    int r = i >> 7, k = i & 127;
    Xt[k * 34 + r] = (r < nr) ? x[(row0 + r) * 128 + k] : 0.f;
  }
  __syncthreads();
  float acc[32];
#pragma unroll
  for (int r = 0; r < 32; ++r) acc[r] = 0.f;
#pragma unroll 4
  for (int k = 0; k < 128; ++k) {
    float w = W[k * 128 + col];
    const float2* xrow = (const float2*)(Xt + k * 34);
#pragma unroll
    for (int rr = 0; rr < 16; ++rr) {
      float2 xv = xrow[rr];
      acc[2 * rr] += xv.x * w;
      acc[2 * rr + 1] += xv.y * w;
    }
  }
  for (int r = 0; r < nr; ++r)
    outp[(row0 + r) * 128 + col] = acc[r] + bia;
}

// ---- K2: per-dst sum of edge_attr + in-degree count (self-loop 'mean') ----
__global__ __launch_bounds__(256) void k_self_hist(
    const int* __restrict__ dst, const float* __restrict__ edge_attr,
    float* __restrict__ self_sum, float* __restrict__ cnt, int E)
{
  int tid = blockIdx.x * 256 + threadIdx.x;
  if (tid >= E * 16) return;
  int e = tid >> 4, k = tid & 15;
  int d = dst[e];
  unsafeAtomicAdd(&self_sum[d * 16 + k], edge_attr[tid]);
  if (k == 0) unsafeAtomicAdd(&cnt[d], 1.f);
}

// ---- K3: per augmented edge: e_emb on the fly, leaky_relu, logit, seg-max --
// 16 threads/edge, each owns 8 channels (head = j>>2).
__global__ __launch_bounds__(256) void k_edge_logits(
    const int* __restrict__ src, const int* __restrict__ dst,
    const float* __restrict__ edge_attr, const float* __restrict__ self_sum,
    const float* __restrict__ cnt, const float* __restrict__ xl,
    const float* __restrict__ xr, const float* __restrict__ We,
    const float* __restrict__ att, float* __restrict__ alpha,
    unsigned* __restrict__ amax, int E, int etot)
{
  __shared__ float sWe[2048];   // [16][128]
  __shared__ float sAtt[128];
  const int t = threadIdx.x;
  for (int i = t; i < 2048; i += 256) sWe[i] = We[i];
  if (t < 128) sAtt[t] = att[t];
  __syncthreads();
  const int e = blockIdx.x * 16 + (t >> 4);
  if (e >= etot) return;
  const int j = t & 15;
  int s, d;
  float ea[16];
  if (e < E) {
    s = src[e];
    d = dst[e];
#pragma unroll
    for (int k = 0; k < 16; ++k) ea[k] = edge_attr[e * 16 + k];
  } else {
    s = d = e - E;
    const float inv = 1.f / fmaxf(cnt[s], 1.f);
#pragma unroll
    for (int k = 0; k < 16; ++k) ea[k] = self_sum[s * 16 + k] * inv;
  }
  const int f0 = j * 8;
  float emb[8];
#pragma unroll
  for (int u = 0; u < 8; ++u) emb[u] = 0.f;
  const float4* sWe4 = (const float4*)sWe;
#pragma unroll
  for (int k = 0; k < 16; ++k) {
    const float a = ea[k];
    float4 w0 = sWe4[k * 32 + j * 2];
    float4 w1 = sWe4[k * 32 + j * 2 + 1];
    emb[0] += a * w0.x; emb[1] += a * w0.y; emb[2] += a * w0.z; emb[3] += a * w0.w;
    emb[4] += a * w1.x; emb[5] += a * w1.y; emb[6] += a * w1.z; emb[7] += a * w1.w;
  }
  const float4 a0 = *(const float4*)(xl + s * 128 + f0);
  const float4 a1 = *(const float4*)(xl + s * 128 + f0 + 4);
  const float4 b0 = *(const float4*)(xr + d * 128 + f0);
  const float4 b1 = *(const float4*)(xr + d * 128 + f0 + 4);
  float mv[8] = {a0.x + b0.x + emb[0], a0.y + b0.y + emb[1],
                 a0.z + b0.z + emb[2], a0.w + b0.w + emb[3],
                 a1.x + b1.x + emb[4], a1.y + b1.y + emb[5],
                 a1.z + b1.z + emb[6], a1.w + b1.w + emb[7]};
  float part = 0.f;
#pragma unroll
  for (int u = 0; u < 8; ++u) {
    float m = mv[u];
    m = (m > 0.f) ? m : NEG_SLOPE * m;
    part += m * sAtt[f0 + u];
  }
  part += __shfl_xor(part, 1);
  part += __shfl_xor(part, 2);
  if ((j & 3) == 0) {
    const int h = j >> 2;
    alpha[e * 4 + h] = part;
    atomicMax(&amax[d * 4 + h], ford(part));
  }
}

// ---- K4: p = exp(logit - amax[dst]); denom[dst] += p ----
__global__ __launch_bounds__(256) void k_exp_denom(
    const int* __restrict__ dst, float* __restrict__ alpha,
    const unsigned* __restrict__ amax, float* __restrict__ denom, int E,
    int etot)
{
  int tid = blockIdx.x * 256 + threadIdx.x;
  if (tid >= etot * 4) return;
  int e = tid >> 2, h = tid & 3;
  int d = (e < E) ? dst[e] : e - E;
  float mx = funord(amax[d * 4 + h]);
  float p = __expf(alpha[tid] - mx);
  alpha[tid] = p;
  unsafeAtomicAdd(&denom[d * 4 + h], p);
}

// ---- K4b: denom -> 1/denom ----
__global__ __launch_bounds__(256) void k_inv(float* __restrict__ denom, int n)
{
  int i = blockIdx.x * 256 + threadIdx.x;
  if (i < n) denom[i] = 1.f / fmaxf(denom[i], 1e-30f);
}

// ---- K5: out[dst] += (p/denom) * xl[src]  (32 threads/edge, float4) ----
__global__ __launch_bounds__(256) void k_scatter(
    const int* __restrict__ src, const int* __restrict__ dst,
    const float* __restrict__ alpha, const float* __restrict__ invden,
    const float* __restrict__ xl, float* __restrict__ out, int E, int etot)
{
  int tid = blockIdx.x * 256 + threadIdx.x;
  if (tid >= etot * 32) return;
  int e = tid >> 5, j = tid & 31;
  int d, s;
  if (e < E) { s = src[e]; d = dst[e]; } else { s = d = e - E; }
  int h = j >> 3;
  float w = alpha[e * 4 + h] * invden[d * 4 + h];
  float4 v = *(const float4*)(xl + s * 128 + j * 4);
  float* o = out + d * 128 + j * 4;
  unsafeAtomicAdd(o + 0, w * v.x);
  unsafeAtomicAdd(o + 1, w * v.y);
  unsafeAtomicAdd(o + 2, w * v.z);
  unsafeAtomicAdd(o + 3, w * v.w);
}

// ---- K6: z = x + acc + bias; global sum & sumsq (graph-mode LayerNorm) ----
__global__ __launch_bounds__(256) void k_znorm_reduce(
    const float* __restrict__ x, const float* __restrict__ acc,
    const float* __restrict__ bias, float* __restrict__ z,
    double* __restrict__ red, int M)
{
  float s = 0.f, s2 = 0.f;
  for (int i = blockIdx.x * 256 + threadIdx.x; i < M; i += gridDim.x * 256) {
    float v = x[i] + acc[i] + bias[i & 127];
    z[i] = v;
    s += v;
    s2 += v * v;
  }
#pragma unroll
  for (int o = 32; o > 0; o >>= 1) {
    s += __shfl_down(s, o);
    s2 += __shfl_down(s2, o);
  }
  __shared__ double ls[4], ls2[4];
  int w = threadIdx.x >> 6;
  if ((threadIdx.x & 63) == 0) { ls[w] = (double)s; ls2[w] = (double)s2; }
  __syncthreads();
  if (threadIdx.x == 0) {
    double S = ls[0] + ls[1] + ls[2] + ls[3];
    double S2 = ls2[0] + ls2[1] + ls2[2] + ls2[3];
    unsafeAtomicAdd(red, S);
    unsafeAtomicAdd(red + 1, S2);
  }
}

// ---- K7: normalize, scale/shift, relu ----
__global__ __launch_bounds__(256) void k_final(
    const float* __restrict__ z, const double* __restrict__ red,
    const float* __restrict__ lnw, const float* __restrict__ lnb,
    float* __restrict__ out, int M)
{
  int i = blockIdx.x * 256 + threadIdx.x;
  if (i >= M) return;
  double invM = 1.0 / (double)M;
  double mu = red[0] * invM;
  double var = red[1] * invM - mu * mu;
  float sc = rsqrtf((float)var + LN_EPS);
  float muf = (float)mu;
  int c = i & 127;
  float v = (z[i] - muf) * sc * lnw[c] + lnb[c];
  out[i] = v > 0.f ? v : 0.f;
}

extern "C" void kernel_launch(void* const* d_in, const int* in_sizes, int n_in,
                              void* d_out, int out_size, void* d_ws,
                              size_t ws_size, hipStream_t stream)
{
  const float* x = (const float*)d_in[0];
  const int* ei = (const int*)d_in[1];
  const float* edge_attr = (const float*)d_in[2];
  const float* Wl = (const float*)d_in[3];
  const float* bl = (const float*)d_in[4];
  const float* Wr = (const float*)d_in[5];
  const float* br = (const float*)d_in[6];
  const float* We = (const float*)d_in[7];
  const float* att = (const float*)d_in[8];
  const float* bias = (const float*)d_in[9];
  const float* lnw = (const float*)d_in[10];
  const float* lnb = (const float*)d_in[11];
  float* out = (float*)d_out;

  const int N = in_sizes[0] / 128;
  const int E = in_sizes[1] / 2;
  const int etot = E + N;
  const int M = N * 128;
  const int* srcp = ei;
  const int* dstp = ei + E;

  // workspace layout (floats): xl | xr(=z) | self_sum | cnt | alpha | amax |
  // denom | red(2 doubles)
  float* ws = (float*)d_ws;
  float* xl = ws;
  float* xr = xl + (size_t)M;
  float* self_sum = xr + (size_t)M;
  float* cnt = self_sum + (size_t)N * 16;
  float* alpha = cnt + (size_t)N;
  unsigned* amax = (unsigned*)(alpha + (size_t)etot * 4);
  float* denom = (float*)(amax + (size_t)N * 4);
  double* red = (double*)(denom + (size_t)N * 4);
  float* z = xr;  // xr is dead after k_edge_logits

  hipMemsetAsync(out, 0, (size_t)M * 4, stream);
  hipMemsetAsync(self_sum, 0, (size_t)N * 16 * 4, stream);
  hipMemsetAsync(cnt, 0, (size_t)N * 4, stream);
  hipMemsetAsync(amax, 0, (size_t)N * 4 * 4, stream);
  hipMemsetAsync(denom, 0, (size_t)N * 4 * 4, stream);
  hipMemsetAsync(red, 0, 16, stream);

  k_gemm_xlxr<<<(N + 31) / 32, 256, 0, stream>>>(x, Wl, bl, Wr, br, xl, xr, N);
  k_self_hist<<<(E * 16 + 255) / 256, 256, 0, stream>>>(dstp, edge_attr,
                                                        self_sum, cnt, E);
  k_edge_logits<<<(etot + 15) / 16, 256, 0, stream>>>(
      srcp, dstp, edge_attr, self_sum, cnt, xl, xr, We, att, alpha, amax, E,
      etot);
  k_exp_denom<<<(etot * 4 + 255) / 256, 256, 0, stream>>>(dstp, alpha, amax,
                                                          denom, E, etot);
  k_inv<<<(N * 4 + 255) / 256, 256, 0, stream>>>(denom, N * 4);
  k_scatter<<<(int)(((long long)etot * 32 + 255) / 256), 256, 0, stream>>>(
      srcp, dstp, alpha, denom, xl, out, E, etot);
  k_znorm_reduce<<<2048, 256, 0, stream>>>(x, out, bias, z, red, M);
  k_final<<<(M + 255) / 256, 256, 0, stream>>>(z, red, lnw, lnb, out, M);
}

// Round 2
// 1133.644 us; speedup vs baseline: 3.3891x; 3.3891x over previous
//
#include <hip/hip_runtime.h>
#include <hip/hip_bf16.h>

static constexpr float NEG_SLOPE = 0.2f;
static constexpr float LN_EPS = 1e-5f;

// ---- K1: xl = x@Wl + bl ; xr = x@Wr + br  (fused, 32 rows/block) ----
__global__ __launch_bounds__(256) void k_gemm_xlxr(
    const float* __restrict__ x, const float* __restrict__ Wl,
    const float* __restrict__ bl, const float* __restrict__ Wr,
    const float* __restrict__ br, float* __restrict__ xl,
    float* __restrict__ xr, int n)
{
  __shared__ float Xt[128 * 34];
  const int t = threadIdx.x;
  const int col = t & 127;
  const bool isR = t >= 128;
  const float* __restrict__ W = isR ? Wr : Wl;
  float* __restrict__ outp = isR ? xr : xl;
  const float bia = isR ? br[col] : bl[col];
  const int row0 = blockIdx.x * 32;
  const int nr = min(32, n - row0);
  for (int i = t; i < 32 * 128; i += 256) {
    int r = i >> 7, k = i & 127;
    Xt[k * 34 + r] = (r < nr) ? x[(row0 + r) * 128 + k] : 0.f;
  }
  __syncthreads();
  float acc[32];
#pragma unroll
  for (int r = 0; r < 32; ++r) acc[r] = 0.f;
#pragma unroll 4
  for (int k = 0; k < 128; ++k) {
    float w = W[k * 128 + col];
    const float2* xrow = (const float2*)(Xt + k * 34);
#pragma unroll
    for (int rr = 0; rr < 16; ++rr) {
      float2 xv = xrow[rr];
      acc[2 * rr] += xv.x * w;
      acc[2 * rr + 1] += xv.y * w;
    }
  }
  for (int r = 0; r < nr; ++r)
    outp[(row0 + r) * 128 + col] = acc[r] + bia;
}

// ---- K2: in-degree per dst (int atomics) ----
__global__ __launch_bounds__(256) void k_count(const int* __restrict__ dst,
                                               int* __restrict__ deg, int E)
{
  int e = blockIdx.x * 256 + threadIdx.x;
  if (e < E) atomicAdd(&deg[dst[e]], 1);
}

// ---- K3a/b/c: exclusive prefix scan of (deg[i]+1) -> offs ----
__global__ __launch_bounds__(256) void k_scan1(const int* __restrict__ deg,
                                               int* __restrict__ bsum, int n)
{
  int i = blockIdx.x * 256 + threadIdx.x;
  int v = (i < n) ? deg[i] + 1 : 0;
#pragma unroll
  for (int o = 32; o > 0; o >>= 1) v += __shfl_down(v, o);
  __shared__ int ls[4];
  if ((threadIdx.x & 63) == 0) ls[threadIdx.x >> 6] = v;
  __syncthreads();
  if (threadIdx.x == 0) bsum[blockIdx.x] = ls[0] + ls[1] + ls[2] + ls[3];
}

__global__ __launch_bounds__(512) void k_scan2(int* __restrict__ bsum, int nb)
{
  __shared__ int s[512];
  int t = threadIdx.x;
  int v = (t < nb) ? bsum[t] : 0;
  s[t] = v;
  __syncthreads();
  for (int o = 1; o < 512; o <<= 1) {
    int u = (t >= o) ? s[t - o] : 0;
    __syncthreads();
    s[t] += u;
    __syncthreads();
  }
  if (t < nb) bsum[t] = s[t] - v;  // exclusive
}

__global__ __launch_bounds__(256) void k_scan3(const int* __restrict__ deg,
                                               const int* __restrict__ bsum,
                                               int* __restrict__ offs, int n)
{
  __shared__ int s[256];
  int b = blockIdx.x, t = threadIdx.x, i = b * 256 + t;
  int v = (i < n) ? deg[i] + 1 : 0;
  s[t] = v;
  __syncthreads();
  for (int o = 1; o < 256; o <<= 1) {
    int u = (t >= o) ? s[t - o] : 0;
    __syncthreads();
    s[t] += u;
    __syncthreads();
  }
  if (i < n) offs[i] = bsum[b] + s[t] - v;
}

// ---- K4: fill CSR. Self-loop at segment head; real edges after. ----
__global__ __launch_bounds__(256) void k_fill_self(const int* __restrict__ offs,
                                                   int* __restrict__ ssrc,
                                                   int* __restrict__ seid,
                                                   int N, int E)
{
  int d = blockIdx.x * 256 + threadIdx.x;
  if (d >= N) return;
  int pos = offs[d];
  ssrc[pos] = d;
  seid[pos] = E + d;
}

__global__ __launch_bounds__(256) void k_fill(
    const int* __restrict__ src, const int* __restrict__ dst,
    const int* __restrict__ offs, int* __restrict__ cursor,
    int* __restrict__ ssrc, int* __restrict__ seid, int E)
{
  int e = blockIdx.x * 256 + threadIdx.x;
  if (e >= E) return;
  int d = dst[e];
  int pos = offs[d] + 1 + atomicAdd(&cursor[d], 1);
  ssrc[pos] = src[e];
  seid[pos] = e;
}

// ---- K5: self-loop attr = mean of incoming edge_attr (16 lanes/node) ----
__global__ __launch_bounds__(256) void k_selfmean(
    const int* __restrict__ seid, const int* __restrict__ offs,
    const int* __restrict__ deg, const float* __restrict__ edge_attr,
    float* __restrict__ self_attr, int N)
{
  int node = blockIdx.x * 16 + (threadIdx.x >> 4);
  if (node >= N) return;
  int k = threadIdx.x & 15;
  int beg = offs[node] + 1;  // skip self slot
  int d = deg[node];
  float s = 0.f;
  for (int q = 0; q < d; ++q) {
    int eid = seid[beg + q];
    s += edge_attr[eid * 16 + k];
  }
  self_attr[node * 16 + k] = s / fmaxf((float)d, 1.f);
}

// ---- K6: per augmented edge: e_emb on the fly, leaky_relu, logit ----
__global__ __launch_bounds__(256) void k_edge_logits(
    const int* __restrict__ src, const int* __restrict__ dst,
    const float* __restrict__ edge_attr, const float* __restrict__ self_attr,
    const float* __restrict__ xl, const float* __restrict__ xr,
    const float* __restrict__ We, const float* __restrict__ att,
    float* __restrict__ alpha, int E, int etot)
{
  __shared__ float sWe[2048];  // [16][128]
  __shared__ float sAtt[128];
  const int t = threadIdx.x;
  for (int i = t; i < 2048; i += 256) sWe[i] = We[i];
  if (t < 128) sAtt[t] = att[t];
  __syncthreads();
  const int e = blockIdx.x * 16 + (t >> 4);
  if (e >= etot) return;
  const int j = t & 15;
  int s, d;
  float ea[16];
  if (e < E) {
    s = src[e];
    d = dst[e];
#pragma unroll
    for (int k = 0; k < 16; ++k) ea[k] = edge_attr[e * 16 + k];
  } else {
    s = d = e - E;
#pragma unroll
    for (int k = 0; k < 16; ++k) ea[k] = self_attr[s * 16 + k];
  }
  const int f0 = j * 8;
  float emb[8];
#pragma unroll
  for (int u = 0; u < 8; ++u) emb[u] = 0.f;
  const float4* sWe4 = (const float4*)sWe;
#pragma unroll
  for (int k = 0; k < 16; ++k) {
    const float a = ea[k];
    float4 w0 = sWe4[k * 32 + j * 2];
    float4 w1 = sWe4[k * 32 + j * 2 + 1];
    emb[0] += a * w0.x; emb[1] += a * w0.y; emb[2] += a * w0.z; emb[3] += a * w0.w;
    emb[4] += a * w1.x; emb[5] += a * w1.y; emb[6] += a * w1.z; emb[7] += a * w1.w;
  }
  const float4 a0 = *(const float4*)(xl + (size_t)s * 128 + f0);
  const float4 a1 = *(const float4*)(xl + (size_t)s * 128 + f0 + 4);
  const float4 b0 = *(const float4*)(xr + (size_t)d * 128 + f0);
  const float4 b1 = *(const float4*)(xr + (size_t)d * 128 + f0 + 4);
  float mv[8] = {a0.x + b0.x + emb[0], a0.y + b0.y + emb[1],
                 a0.z + b0.z + emb[2], a0.w + b0.w + emb[3],
                 a1.x + b1.x + emb[4], a1.y + b1.y + emb[5],
                 a1.z + b1.z + emb[6], a1.w + b1.w + emb[7]};
  float part = 0.f;
#pragma unroll
  for (int u = 0; u < 8; ++u) {
    float m = mv[u];
    m = (m > 0.f) ? m : NEG_SLOPE * m;
    part += m * sAtt[f0 + u];
  }
  part += __shfl_xor(part, 1);
  part += __shfl_xor(part, 2);
  if ((j & 3) == 0) alpha[e * 4 + (j >> 2)] = part;
}

// ---- K7: per-node gather: max, exp, denom, weighted sum, write (no atomics)
__global__ __launch_bounds__(256) void k_gather(
    const int* __restrict__ ssrc, const int* __restrict__ seid,
    const int* __restrict__ offs, const int* __restrict__ deg,
    const float* __restrict__ alpha, const float* __restrict__ xl,
    float* __restrict__ out, int N)
{
  int node = blockIdx.x * 4 + (threadIdx.x >> 6);
  if (node >= N) return;
  const int j = threadIdx.x & 63;
  const int h = j >> 4;  // lane's head (channels 2j,2j+1 in [32h,32h+32))
  const int beg = offs[node];
  const int len = deg[node] + 1;
  float mx = -1e30f;
  for (int q = 0; q < len; ++q) {
    int eid = seid[beg + q];
    mx = fmaxf(mx, alpha[eid * 4 + h]);
  }
  float den = 0.f, ax = 0.f, ay = 0.f;
  for (int q = 0; q < len; ++q) {
    int eid = seid[beg + q];
    int sid = ssrc[beg + q];
    float p = __expf(alpha[eid * 4 + h] - mx);
    den += p;
    float2 v = *(const float2*)(xl + (size_t)sid * 128 + j * 2);
    ax += p * v.x;
    ay += p * v.y;
  }
  float inv = 1.f / den;
  *(float2*)(out + (size_t)node * 128 + j * 2) = make_float2(ax * inv, ay * inv);
}

// ---- K8: z = x + acc + bias; global sum & sumsq ----
__global__ __launch_bounds__(256) void k_znorm_reduce(
    const float* __restrict__ x, const float* __restrict__ acc,
    const float* __restrict__ bias, float* __restrict__ z,
    double* __restrict__ red, int M)
{
  float s = 0.f, s2 = 0.f;
  for (int i = blockIdx.x * 256 + threadIdx.x; i < M; i += gridDim.x * 256) {
    float v = x[i] + acc[i] + bias[i & 127];
    z[i] = v;
    s += v;
    s2 += v * v;
  }
#pragma unroll
  for (int o = 32; o > 0; o >>= 1) {
    s += __shfl_down(s, o);
    s2 += __shfl_down(s2, o);
  }
  __shared__ double ls[4], ls2[4];
  int w = threadIdx.x >> 6;
  if ((threadIdx.x & 63) == 0) { ls[w] = (double)s; ls2[w] = (double)s2; }
  __syncthreads();
  if (threadIdx.x == 0) {
    double S = ls[0] + ls[1] + ls[2] + ls[3];
    double S2 = ls2[0] + ls2[1] + ls2[2] + ls2[3];
    unsafeAtomicAdd(red, S);
    unsafeAtomicAdd(red + 1, S2);
  }
}

// ---- K9: normalize, scale/shift, relu ----
__global__ __launch_bounds__(256) void k_final(
    const float* __restrict__ z, const double* __restrict__ red,
    const float* __restrict__ lnw, const float* __restrict__ lnb,
    float* __restrict__ out, int M)
{
  int i = blockIdx.x * 256 + threadIdx.x;
  if (i >= M) return;
  double invM = 1.0 / (double)M;
  double mu = red[0] * invM;
  double var = red[1] * invM - mu * mu;
  float sc = rsqrtf((float)var + LN_EPS);
  float muf = (float)mu;
  int c = i & 127;
  float v = (z[i] - muf) * sc * lnw[c] + lnb[c];
  out[i] = v > 0.f ? v : 0.f;
}

extern "C" void kernel_launch(void* const* d_in, const int* in_sizes, int n_in,
                              void* d_out, int out_size, void* d_ws,
                              size_t ws_size, hipStream_t stream)
{
  const float* x = (const float*)d_in[0];
  const int* ei = (const int*)d_in[1];
  const float* edge_attr = (const float*)d_in[2];
  const float* Wl = (const float*)d_in[3];
  const float* bl = (const float*)d_in[4];
  const float* Wr = (const float*)d_in[5];
  const float* br = (const float*)d_in[6];
  const float* We = (const float*)d_in[7];
  const float* att = (const float*)d_in[8];
  const float* bias = (const float*)d_in[9];
  const float* lnw = (const float*)d_in[10];
  const float* lnb = (const float*)d_in[11];
  float* out = (float*)d_out;

  const int N = in_sizes[0] / 128;
  const int E = in_sizes[1] / 2;
  const int etot = E + N;
  const int M = N * 128;
  const int* srcp = ei;
  const int* dstp = ei + E;
  const int nb = (N + 255) / 256;

  // workspace layout
  float* ws = (float*)d_ws;
  float* xl = ws;                               // M
  float* xr = xl + (size_t)M;                   // M  (reused as z)
  float* self_attr = xr + (size_t)M;            // N*16
  float* alpha = self_attr + (size_t)N * 16;    // etot*4
  int* deg = (int*)(alpha + (size_t)etot * 4);  // N
  int* offs = deg + N;                          // N
  int* cursor = offs + N;                       // N
  int* bsum = cursor + N;                       // nb
  int* ssrc = bsum + ((nb + 1) & ~1);           // etot
  int* seid = ssrc + etot;                      // etot
  double* red = (double*)((((size_t)(seid + etot)) + 15) & ~(size_t)15);
  float* z = xr;

  hipMemsetAsync(deg, 0, (size_t)N * 4, stream);
  hipMemsetAsync(cursor, 0, (size_t)N * 4, stream);
  hipMemsetAsync(red, 0, 16, stream);

  k_gemm_xlxr<<<(N + 31) / 32, 256, 0, stream>>>(x, Wl, bl, Wr, br, xl, xr, N);
  k_count<<<(E + 255) / 256, 256, 0, stream>>>(dstp, deg, E);
  k_scan1<<<nb, 256, 0, stream>>>(deg, bsum, N);
  k_scan2<<<1, 512, 0, stream>>>(bsum, nb);
  k_scan3<<<nb, 256, 0, stream>>>(deg, bsum, offs, N);
  k_fill_self<<<nb, 256, 0, stream>>>(offs, ssrc, seid, N, E);
  k_fill<<<(E + 255) / 256, 256, 0, stream>>>(srcp, dstp, offs, cursor, ssrc,
                                              seid, E);
  k_selfmean<<<(N + 15) / 16, 256, 0, stream>>>(seid, offs, deg, edge_attr,
                                                self_attr, N);
  k_edge_logits<<<(etot + 15) / 16, 256, 0, stream>>>(
      srcp, dstp, edge_attr, self_attr, xl, xr, We, att, alpha, E, etot);
  k_gather<<<(N + 3) / 4, 256, 0, stream>>>(ssrc, seid, offs, deg, alpha, xl,
                                            out, N);
  k_znorm_reduce<<<2048, 256, 0, stream>>>(x, out, bias, z, red, M);
  k_final<<<(M + 255) / 256, 256, 0, stream>>>(z, red, lnw, lnb, out, M);
}

// Round 3
// 848.512 us; speedup vs baseline: 4.5279x; 1.3360x over previous
//
#include <hip/hip_runtime.h>
#include <hip/hip_bf16.h>

static constexpr float NEG_SLOPE = 0.2f;
static constexpr float LN_EPS = 1e-5f;

// ---- K1: xl = x@Wl + bl ; xr = x@Wr + br  (fused, 32 rows/block) ----
__global__ __launch_bounds__(256) void k_gemm_xlxr(
    const float* __restrict__ x, const float* __restrict__ Wl,
    const float* __restrict__ bl, const float* __restrict__ Wr,
    const float* __restrict__ br, float* __restrict__ xl,
    float* __restrict__ xr, int n)
{
  __shared__ float Xt[128 * 34];
  const int t = threadIdx.x;
  const int col = t & 127;
  const bool isR = t >= 128;
  const float* __restrict__ W = isR ? Wr : Wl;
  float* __restrict__ outp = isR ? xr : xl;
  const float bia = isR ? br[col] : bl[col];
  const int row0 = blockIdx.x * 32;
  const int nr = min(32, n - row0);
  for (int i = t; i < 32 * 128; i += 256) {
    int r = i >> 7, k = i & 127;
    Xt[k * 34 + r] = (r < nr) ? x[(row0 + r) * 128 + k] : 0.f;
  }
  __syncthreads();
  float acc[32];
#pragma unroll
  for (int r = 0; r < 32; ++r) acc[r] = 0.f;
#pragma unroll 4
  for (int k = 0; k < 128; ++k) {
    float w = W[k * 128 + col];
    const float2* xrow = (const float2*)(Xt + k * 34);
#pragma unroll
    for (int rr = 0; rr < 16; ++rr) {
      float2 xv = xrow[rr];
      acc[2 * rr] += xv.x * w;
      acc[2 * rr + 1] += xv.y * w;
    }
  }
  for (int r = 0; r < nr; ++r)
    outp[(row0 + r) * 128 + col] = acc[r] + bia;
}

// ---- K2: in-degree per dst ----
__global__ __launch_bounds__(256) void k_count(const int* __restrict__ dst,
                                               int* __restrict__ deg, int E)
{
  int e = blockIdx.x * 256 + threadIdx.x;
  if (e < E) atomicAdd(&deg[dst[e]], 1);
}

// ---- K3a/b/c: exclusive prefix scan of deg -> offs ----
__global__ __launch_bounds__(256) void k_scan1(const int* __restrict__ deg,
                                               int* __restrict__ bsum, int n)
{
  int i = blockIdx.x * 256 + threadIdx.x;
  int v = (i < n) ? deg[i] : 0;
#pragma unroll
  for (int o = 32; o > 0; o >>= 1) v += __shfl_down(v, o);
  __shared__ int ls[4];
  if ((threadIdx.x & 63) == 0) ls[threadIdx.x >> 6] = v;
  __syncthreads();
  if (threadIdx.x == 0) bsum[blockIdx.x] = ls[0] + ls[1] + ls[2] + ls[3];
}

__global__ __launch_bounds__(512) void k_scan2(int* __restrict__ bsum, int nb)
{
  __shared__ int s[512];
  int t = threadIdx.x;
  int v = (t < nb) ? bsum[t] : 0;
  s[t] = v;
  __syncthreads();
  for (int o = 1; o < 512; o <<= 1) {
    int u = (t >= o) ? s[t - o] : 0;
    __syncthreads();
    s[t] += u;
    __syncthreads();
  }
  if (t < nb) bsum[t] = s[t] - v;  // exclusive
}

__global__ __launch_bounds__(256) void k_scan3(const int* __restrict__ deg,
                                               const int* __restrict__ bsum,
                                               int* __restrict__ offs, int n)
{
  __shared__ int s[256];
  int b = blockIdx.x, t = threadIdx.x, i = b * 256 + t;
  int v = (i < n) ? deg[i] : 0;
  s[t] = v;
  __syncthreads();
  for (int o = 1; o < 256; o <<= 1) {
    int u = (t >= o) ? s[t - o] : 0;
    __syncthreads();
    s[t] += u;
    __syncthreads();
  }
  if (i < n) offs[i] = bsum[b] + s[t] - v;
}

// ---- K4: fill dst-CSR (src id + edge id per slot) ----
__global__ __launch_bounds__(256) void k_fill(
    const int* __restrict__ src, const int* __restrict__ dst,
    const int* __restrict__ offs, int* __restrict__ cursor,
    int* __restrict__ ssrc, int* __restrict__ seid, int E)
{
  int e = blockIdx.x * 256 + threadIdx.x;
  if (e >= E) return;
  int d = dst[e];
  int pos = offs[d] + atomicAdd(&cursor[d], 1);
  ssrc[pos] = src[e];
  seid[pos] = e;
}

// ---- K5: fused per-node logits + online softmax + aggregation ----
// One 64-lane wave per node; lane j owns channels {2j, 2j+1}; head = j>>4.
// We[:, 2j..2j+1] lives in 32 VGPRs; ea broadcast via readlane.
__global__ __launch_bounds__(256) void k_fused(
    const int* __restrict__ ssrc, const int* __restrict__ seid,
    const int* __restrict__ offs, const int* __restrict__ deg,
    const float* __restrict__ edge_attr, const float* __restrict__ xl,
    const float* __restrict__ xr, const float* __restrict__ We,
    const float* __restrict__ att, float* __restrict__ out, int N)
{
  const int lane = threadIdx.x & 63;
  const int gw = blockIdx.x * 4 + (threadIdx.x >> 6);
  const int nw = gridDim.x * 4;
  const float2* __restrict__ We2 = (const float2*)We;
  const float2* __restrict__ Xl2 = (const float2*)xl;
  const float2* __restrict__ Xr2 = (const float2*)xr;
  float2* __restrict__ Out2 = (float2*)out;

  float we0[16], we1[16];
#pragma unroll
  for (int k = 0; k < 16; ++k) {
    float2 w = We2[k * 64 + lane];
    we0[k] = w.x;
    we1[k] = w.y;
  }
  const float2 a2 = ((const float2*)att)[lane];

  for (int node = gw; node < N; node += nw) {
    const int beg = offs[node];
    const int len = deg[node];
    const float2 xr2 = Xr2[(size_t)node * 64 + lane];
    float easum = 0.f, m = -1e30f, den = 0.f, acc0 = 0.f, acc1 = 0.f;

    int s_nx = node;
    float ea_nx = 0.f;
    if (len > 0) {
      s_nx = ssrc[beg];
      int e_nx = seid[beg];
      ea_nx = (lane < 16) ? edge_attr[(size_t)e_nx * 16 + lane] : 0.f;
    }

    for (int q = 0; q <= len; ++q) {
      const int s_cur = s_nx;
      float eav = ea_nx;
      if (q < len) {
        easum += eav;
        if (q + 1 < len) {
          s_nx = ssrc[beg + q + 1];
          int e_nx = seid[beg + q + 1];
          ea_nx = (lane < 16) ? edge_attr[(size_t)e_nx * 16 + lane] : 0.f;
        } else {
          // next iteration is the self loop
          s_nx = node;
        }
      }
      if (q == len) {  // self loop: ea = mean of incoming edge_attr
        const float inv = (len > 0) ? 1.f / (float)len : 0.f;
        eav = easum * inv;
      }
      // emb = ea @ We (our 2 channels)
      float emb0 = 0.f, emb1 = 0.f;
#pragma unroll
      for (int k = 0; k < 16; ++k) {
        float eak = __int_as_float(
            __builtin_amdgcn_readlane(__float_as_int(eav), k));
        emb0 = fmaf(eak, we0[k], emb0);
        emb1 = fmaf(eak, we1[k], emb1);
      }
      const float2 xv = Xl2[(size_t)s_cur * 64 + lane];
      float m0 = xv.x + xr2.x + emb0;
      float m1 = xv.y + xr2.y + emb1;
      m0 = fmaxf(m0, NEG_SLOPE * m0);
      m1 = fmaxf(m1, NEG_SLOPE * m1);
      float part = m0 * a2.x + m1 * a2.y;
      part += __shfl_xor(part, 1);
      part += __shfl_xor(part, 2);
      part += __shfl_xor(part, 4);
      part += __shfl_xor(part, 8);
      // branchless online softmax (uniform within each 16-lane head group)
      const float mn = fmaxf(m, part);
      const float c = __expf(m - mn);
      const float p = __expf(part - mn);
      den = den * c + p;
      acc0 = acc0 * c + p * xv.x;
      acc1 = acc1 * c + p * xv.y;
      m = mn;
    }
    const float invden = 1.f / den;
    Out2[(size_t)node * 64 + lane] = make_float2(acc0 * invden, acc1 * invden);
  }
}

// ---- K6: global sum & sumsq of z = x + acc + bias (no z materialized) ----
__global__ __launch_bounds__(256) void k_reduce(
    const float* __restrict__ x, const float* __restrict__ acc,
    const float* __restrict__ bias, double* __restrict__ red, int M4)
{
  const float4* X4 = (const float4*)x;
  const float4* A4 = (const float4*)acc;
  const float4* B4 = (const float4*)bias;
  float s = 0.f, s2 = 0.f;
  for (int i = blockIdx.x * 256 + threadIdx.x; i < M4; i += gridDim.x * 256) {
    float4 xv = X4[i], av = A4[i], bv = B4[i & 31];
    float v0 = xv.x + av.x + bv.x;
    float v1 = xv.y + av.y + bv.y;
    float v2 = xv.z + av.z + bv.z;
    float v3 = xv.w + av.w + bv.w;
    s += (v0 + v1) + (v2 + v3);
    s2 += (v0 * v0 + v1 * v1) + (v2 * v2 + v3 * v3);
  }
#pragma unroll
  for (int o = 32; o > 0; o >>= 1) {
    s += __shfl_down(s, o);
    s2 += __shfl_down(s2, o);
  }
  __shared__ double ls[4], ls2[4];
  int w = threadIdx.x >> 6;
  if ((threadIdx.x & 63) == 0) { ls[w] = (double)s; ls2[w] = (double)s2; }
  __syncthreads();
  if (threadIdx.x == 0) {
    unsafeAtomicAdd(red, ls[0] + ls[1] + ls[2] + ls[3]);
    unsafeAtomicAdd(red + 1, ls2[0] + ls2[1] + ls2[2] + ls2[3]);
  }
}

// ---- K7: z = x+acc+bias, normalize, scale/shift, relu (in place on acc) ----
__global__ __launch_bounds__(256) void k_final(
    const float* __restrict__ x, float* __restrict__ acc,
    const float* __restrict__ bias, const double* __restrict__ red,
    const float* __restrict__ lnw, const float* __restrict__ lnb, int M4)
{
  int i = blockIdx.x * 256 + threadIdx.x;
  if (i >= M4) return;
  const double invM = 1.0 / ((double)M4 * 4.0);
  const double mu = red[0] * invM;
  const double var = red[1] * invM - mu * mu;
  const float sc = rsqrtf((float)var + LN_EPS);
  const float muf = (float)mu;
  const float4* X4 = (const float4*)x;
  const float4* B4 = (const float4*)bias;
  const float4* W4 = (const float4*)lnw;
  const float4* L4 = (const float4*)lnb;
  float4* A4 = (float4*)acc;
  float4 xv = X4[i], av = A4[i], bv = B4[i & 31], wv = W4[i & 31],
         lv = L4[i & 31];
  float4 o;
  o.x = fmaxf(((xv.x + av.x + bv.x) - muf) * sc * wv.x + lv.x, 0.f);
  o.y = fmaxf(((xv.y + av.y + bv.y) - muf) * sc * wv.y + lv.y, 0.f);
  o.z = fmaxf(((xv.z + av.z + bv.z) - muf) * sc * wv.z + lv.z, 0.f);
  o.w = fmaxf(((xv.w + av.w + bv.w) - muf) * sc * wv.w + lv.w, 0.f);
  A4[i] = o;
}

extern "C" void kernel_launch(void* const* d_in, const int* in_sizes, int n_in,
                              void* d_out, int out_size, void* d_ws,
                              size_t ws_size, hipStream_t stream)
{
  const float* x = (const float*)d_in[0];
  const int* ei = (const int*)d_in[1];
  const float* edge_attr = (const float*)d_in[2];
  const float* Wl = (const float*)d_in[3];
  const float* bl = (const float*)d_in[4];
  const float* Wr = (const float*)d_in[5];
  const float* br = (const float*)d_in[6];
  const float* We = (const float*)d_in[7];
  const float* att = (const float*)d_in[8];
  const float* bias = (const float*)d_in[9];
  const float* lnw = (const float*)d_in[10];
  const float* lnb = (const float*)d_in[11];
  float* out = (float*)d_out;

  const int N = in_sizes[0] / 128;
  const int E = in_sizes[1] / 2;
  const int M = N * 128;
  const int* srcp = ei;
  const int* dstp = ei + E;
  const int nb = (N + 255) / 256;

  // workspace layout
  float* ws = (float*)d_ws;
  float* xl = ws;                       // M
  float* xr = xl + (size_t)M;           // M
  int* deg = (int*)(xr + (size_t)M);    // N
  int* offs = deg + N;                  // N
  int* cursor = offs + N;               // N
  int* bsum = cursor + N;               // nb
  int* ssrc = bsum + ((nb + 1) & ~1);   // E
  int* seid = ssrc + E;                 // E
  double* red = (double*)((((size_t)(seid + E)) + 15) & ~(size_t)15);

  hipMemsetAsync(deg, 0, (size_t)N * 4, stream);
  hipMemsetAsync(cursor, 0, (size_t)N * 4, stream);
  hipMemsetAsync(red, 0, 16, stream);

  k_gemm_xlxr<<<(N + 31) / 32, 256, 0, stream>>>(x, Wl, bl, Wr, br, xl, xr, N);
  k_count<<<(E + 255) / 256, 256, 0, stream>>>(dstp, deg, E);
  k_scan1<<<nb, 256, 0, stream>>>(deg, bsum, N);
  k_scan2<<<1, 512, 0, stream>>>(bsum, nb);
  k_scan3<<<nb, 256, 0, stream>>>(deg, bsum, offs, N);
  k_fill<<<(E + 255) / 256, 256, 0, stream>>>(srcp, dstp, offs, cursor, ssrc,
                                              seid, E);
  k_fused<<<2048, 256, 0, stream>>>(ssrc, seid, offs, deg, edge_attr, xl, xr,
                                    We, att, out, N);
  k_reduce<<<1024, 256, 0, stream>>>(x, out, bias, red, M / 4);
  k_final<<<(M / 4 + 255) / 256, 256, 0, stream>>>(x, out, bias, red, lnw, lnb,
                                                   M / 4);
}

// Round 4
// 773.601 us; speedup vs baseline: 4.9664x; 1.0968x over previous
//
#include <hip/hip_runtime.h>
#include <hip/hip_bf16.h>

static constexpr float NEG_SLOPE = 0.2f;
static constexpr float LN_EPS = 1e-5f;

// ---- 16-lane (head-group) sum via DPP: quad xor1, xor2, row_ror 4, 8 ----
__device__ __forceinline__ float head_sum16(float x) {
  float t;
  t = __int_as_float(__builtin_amdgcn_update_dpp(
      0, __float_as_int(x), 0xB1, 0xF, 0xF, true));  // quad_perm [1,0,3,2]
  x += t;
  t = __int_as_float(__builtin_amdgcn_update_dpp(
      0, __float_as_int(x), 0x4E, 0xF, 0xF, true));  // quad_perm [2,3,0,1]
  x += t;
  t = __int_as_float(__builtin_amdgcn_update_dpp(
      0, __float_as_int(x), 0x124, 0xF, 0xF, true));  // row_ror:4
  x += t;
  t = __int_as_float(__builtin_amdgcn_update_dpp(
      0, __float_as_int(x), 0x128, 0xF, 0xF, true));  // row_ror:8
  x += t;
  return x;
}

// ---- K1: xl = x@Wl + bl ; xr = x@Wr + br  (fused, 32 rows/block) ----
__global__ __launch_bounds__(256) void k_gemm_xlxr(
    const float* __restrict__ x, const float* __restrict__ Wl,
    const float* __restrict__ bl, const float* __restrict__ Wr,
    const float* __restrict__ br, float* __restrict__ xl,
    float* __restrict__ xr, int n)
{
  __shared__ float Xt[128 * 34];
  const int t = threadIdx.x;
  const int col = t & 127;
  const bool isR = t >= 128;
  const float* __restrict__ W = isR ? Wr : Wl;
  float* __restrict__ outp = isR ? xr : xl;
  const float bia = isR ? br[col] : bl[col];
  const int row0 = blockIdx.x * 32;
  const int nr = min(32, n - row0);
  for (int i = t; i < 32 * 128; i += 256) {
    int r = i >> 7, k = i & 127;
    Xt[k * 34 + r] = (r < nr) ? x[(row0 + r) * 128 + k] : 0.f;
  }
  __syncthreads();
  float acc[32];
#pragma unroll
  for (int r = 0; r < 32; ++r) acc[r] = 0.f;
#pragma unroll 4
  for (int k = 0; k < 128; ++k) {
    float w = W[k * 128 + col];
    const float2* xrow = (const float2*)(Xt + k * 34);
#pragma unroll
    for (int rr = 0; rr < 16; ++rr) {
      float2 xv = xrow[rr];
      acc[2 * rr] += xv.x * w;
      acc[2 * rr + 1] += xv.y * w;
    }
  }
  for (int r = 0; r < nr; ++r)
    outp[(row0 + r) * 128 + col] = acc[r] + bia;
}

// ---- K2: in-degree per dst ----
__global__ __launch_bounds__(256) void k_count(const int* __restrict__ dst,
                                               int* __restrict__ deg, int E)
{
  int e = blockIdx.x * 256 + threadIdx.x;
  if (e < E) atomicAdd(&deg[dst[e]], 1);
}

// ---- K3a/b/c: exclusive prefix scan of deg -> offs ----
__global__ __launch_bounds__(256) void k_scan1(const int* __restrict__ deg,
                                               int* __restrict__ bsum, int n)
{
  int i = blockIdx.x * 256 + threadIdx.x;
  int v = (i < n) ? deg[i] : 0;
#pragma unroll
  for (int o = 32; o > 0; o >>= 1) v += __shfl_down(v, o);
  __shared__ int ls[4];
  if ((threadIdx.x & 63) == 0) ls[threadIdx.x >> 6] = v;
  __syncthreads();
  if (threadIdx.x == 0) bsum[blockIdx.x] = ls[0] + ls[1] + ls[2] + ls[3];
}

__global__ __launch_bounds__(512) void k_scan2(int* __restrict__ bsum, int nb)
{
  __shared__ int s[512];
  int t = threadIdx.x;
  int v = (t < nb) ? bsum[t] : 0;
  s[t] = v;
  __syncthreads();
  for (int o = 1; o < 512; o <<= 1) {
    int u = (t >= o) ? s[t - o] : 0;
    __syncthreads();
    s[t] += u;
    __syncthreads();
  }
  if (t < nb) bsum[t] = s[t] - v;  // exclusive
}

__global__ __launch_bounds__(256) void k_scan3(const int* __restrict__ deg,
                                               const int* __restrict__ bsum,
                                               int* __restrict__ offs, int n)
{
  __shared__ int s[256];
  int b = blockIdx.x, t = threadIdx.x, i = b * 256 + t;
  int v = (i < n) ? deg[i] : 0;
  s[t] = v;
  __syncthreads();
  for (int o = 1; o < 256; o <<= 1) {
    int u = (t >= o) ? s[t - o] : 0;
    __syncthreads();
    s[t] += u;
    __syncthreads();
  }
  if (i < n) offs[i] = bsum[b] + s[t] - v;
}

// ---- K4: fill dst-CSR: (src, edge-id) packed int2 ----
__global__ __launch_bounds__(256) void k_fill(
    const int* __restrict__ src, const int* __restrict__ dst,
    const int* __restrict__ offs, int* __restrict__ cursor,
    int2* __restrict__ csr, int E)
{
  int e = blockIdx.x * 256 + threadIdx.x;
  if (e >= E) return;
  int d = dst[e];
  int pos = offs[d] + atomicAdd(&cursor[d], 1);
  csr[pos] = make_int2(src[e], e);
}

// ---- K5: fused logits + online softmax + aggregation + LN-stat reduce ----
// One 64-lane wave per node; lane j owns channels {2j,2j+1}; head = j>>4.
// Two independent softmax streams (front/back half of segment) for ILP.
__global__ __launch_bounds__(256) void k_fused(
    const int2* __restrict__ csr, const int* __restrict__ offs,
    const int* __restrict__ deg, const float* __restrict__ edge_attr,
    const float* __restrict__ xl, const float* __restrict__ xr,
    const float* __restrict__ We, const float* __restrict__ att,
    const float* __restrict__ x, const float* __restrict__ bias,
    float* __restrict__ out, double* __restrict__ red, int N)
{
  const int lane = threadIdx.x & 63;
  const int gw = blockIdx.x * 4 + (threadIdx.x >> 6);
  const int nw = gridDim.x * 4;
  const float2* __restrict__ We2 = (const float2*)We;
  const float2* __restrict__ Xl2 = (const float2*)xl;
  const float2* __restrict__ Xr2 = (const float2*)xr;
  const float2* __restrict__ X2 = (const float2*)x;
  float2* __restrict__ Out2 = (float2*)out;

  float we0[16], we1[16];
#pragma unroll
  for (int k = 0; k < 16; ++k) {
    float2 w = We2[k * 64 + lane];
    we0[k] = w.x;
    we1[k] = w.y;
  }
  const float2 a2 = ((const float2*)att)[lane];
  const float2 b2 = ((const float2*)bias)[lane];

  float sred = 0.f, s2red = 0.f;

  for (int node = gw; node < N; node += nw) {
    const int beg = offs[node];
    const int len = deg[node];
    const float2 xrv = Xr2[(size_t)node * 64 + lane];

    float mA = -1e30f, dA = 0.f, aA0 = 0.f, aA1 = 0.f, esA = 0.f;
    float mB = -1e30f, dB = 0.f, aB0 = 0.f, aB1 = 0.f, esB = 0.f;

    auto edge = [&](int sid, float eav, float& m, float& den, float& a0,
                    float& a1) {
      float emb0 = 0.f, emb1 = 0.f;
#pragma unroll
      for (int k = 0; k < 16; ++k) {
        float eak = __int_as_float(
            __builtin_amdgcn_readlane(__float_as_int(eav), k));
        emb0 = fmaf(eak, we0[k], emb0);
        emb1 = fmaf(eak, we1[k], emb1);
      }
      const float2 xv = Xl2[(size_t)sid * 64 + lane];
      float m0 = xv.x + xrv.x + emb0;
      float m1 = xv.y + xrv.y + emb1;
      m0 = fmaxf(m0, NEG_SLOPE * m0);
      m1 = fmaxf(m1, NEG_SLOPE * m1);
      const float part = head_sum16(fmaf(m1, a2.y, m0 * a2.x));
      const float mn = fmaxf(m, part);
      const float c = __expf(m - mn);
      const float p = __expf(part - mn);
      den = fmaf(den, c, p);
      a0 = fmaf(a0, c, p * xv.x);
      a1 = fmaf(a1, c, p * xv.y);
      m = mn;
    };

    const int h = len >> 1;
    const bool odd = (len & 1) != 0;

    // prefetch tail edge (if any) and first pair
    int2 cT;
    float eaT = 0.f;
    if (odd) {
      cT = csr[beg + len - 1];
      eaT = (lane < 16) ? edge_attr[(size_t)cT.y * 16 + lane] : 0.f;
    }
    int2 cA, cB;
    float eaA = 0.f, eaB = 0.f;
    if (h > 0) {
      cA = csr[beg];
      cB = csr[beg + h];
      eaA = (lane < 16) ? edge_attr[(size_t)cA.y * 16 + lane] : 0.f;
      eaB = (lane < 16) ? edge_attr[(size_t)cB.y * 16 + lane] : 0.f;
    }
    for (int i = 0; i < h; ++i) {
      const int sA = cA.x, sB = cB.x;
      const float eA = eaA, eB = eaB;
      if (i + 1 < h) {
        cA = csr[beg + i + 1];
        cB = csr[beg + h + i + 1];
        eaA = (lane < 16) ? edge_attr[(size_t)cA.y * 16 + lane] : 0.f;
        eaB = (lane < 16) ? edge_attr[(size_t)cB.y * 16 + lane] : 0.f;
      }
      esA += eA;
      esB += eB;
      edge(sA, eA, mA, dA, aA0, aA1);
      edge(sB, eB, mB, dB, aB0, aB1);
    }
    if (odd) {
      esA += eaT;
      edge(cT.x, eaT, mA, dA, aA0, aA1);
    }
    // self loop: ea = mean of incoming edge_attr (0 if isolated)
    const float inv = (len > 0) ? 1.f / (float)len : 0.f;
    edge(node, (esA + esB) * inv, mA, dA, aA0, aA1);

    // merge stream B into A
    const float mn = fmaxf(mA, mB);
    const float cA2 = __expf(mA - mn);
    const float cB2 = __expf(mB - mn);
    const float den = dA * cA2 + dB * cB2;
    const float invden = 1.f / den;
    const float o0 = (aA0 * cA2 + aB0 * cB2) * invden;
    const float o1 = (aA1 * cA2 + aB1 * cB2) * invden;
    Out2[(size_t)node * 64 + lane] = make_float2(o0, o1);

    // LN stats of z = x + o + bias
    const float2 xvn = X2[(size_t)node * 64 + lane];
    const float v0 = xvn.x + o0 + b2.x;
    const float v1 = xvn.y + o1 + b2.y;
    sred += v0 + v1;
    s2red += v0 * v0 + v1 * v1;
  }

  // block reduction of LN stats
#pragma unroll
  for (int o = 32; o > 0; o >>= 1) {
    sred += __shfl_down(sred, o);
    s2red += __shfl_down(s2red, o);
  }
  __shared__ double ls[4], ls2[4];
  const int w = threadIdx.x >> 6;
  if ((threadIdx.x & 63) == 0) {
    ls[w] = (double)sred;
    ls2[w] = (double)s2red;
  }
  __syncthreads();
  if (threadIdx.x == 0) {
    unsafeAtomicAdd(red, ls[0] + ls[1] + ls[2] + ls[3]);
    unsafeAtomicAdd(red + 1, ls2[0] + ls2[1] + ls2[2] + ls2[3]);
  }
}

// ---- K6: z = x+acc+bias, normalize, scale/shift, relu (in place on acc) ----
__global__ __launch_bounds__(256) void k_final(
    const float* __restrict__ x, float* __restrict__ acc,
    const float* __restrict__ bias, const double* __restrict__ red,
    const float* __restrict__ lnw, const float* __restrict__ lnb, int M4)
{
  int i = blockIdx.x * 256 + threadIdx.x;
  if (i >= M4) return;
  const double invM = 1.0 / ((double)M4 * 4.0);
  const double mu = red[0] * invM;
  const double var = red[1] * invM - mu * mu;
  const float sc = rsqrtf((float)var + LN_EPS);
  const float muf = (float)mu;
  const float4* X4 = (const float4*)x;
  const float4* B4 = (const float4*)bias;
  const float4* W4 = (const float4*)lnw;
  const float4* L4 = (const float4*)lnb;
  float4* A4 = (float4*)acc;
  float4 xv = X4[i], av = A4[i], bv = B4[i & 31], wv = W4[i & 31],
         lv = L4[i & 31];
  float4 o;
  o.x = fmaxf(((xv.x + av.x + bv.x) - muf) * sc * wv.x + lv.x, 0.f);
  o.y = fmaxf(((xv.y + av.y + bv.y) - muf) * sc * wv.y + lv.y, 0.f);
  o.z = fmaxf(((xv.z + av.z + bv.z) - muf) * sc * wv.z + lv.z, 0.f);
  o.w = fmaxf(((xv.w + av.w + bv.w) - muf) * sc * wv.w + lv.w, 0.f);
  A4[i] = o;
}

extern "C" void kernel_launch(void* const* d_in, const int* in_sizes, int n_in,
                              void* d_out, int out_size, void* d_ws,
                              size_t ws_size, hipStream_t stream)
{
  const float* x = (const float*)d_in[0];
  const int* ei = (const int*)d_in[1];
  const float* edge_attr = (const float*)d_in[2];
  const float* Wl = (const float*)d_in[3];
  const float* bl = (const float*)d_in[4];
  const float* Wr = (const float*)d_in[5];
  const float* br = (const float*)d_in[6];
  const float* We = (const float*)d_in[7];
  const float* att = (const float*)d_in[8];
  const float* bias = (const float*)d_in[9];
  const float* lnw = (const float*)d_in[10];
  const float* lnb = (const float*)d_in[11];
  float* out = (float*)d_out;

  const int N = in_sizes[0] / 128;
  const int E = in_sizes[1] / 2;
  const int M = N * 128;
  const int* srcp = ei;
  const int* dstp = ei + E;
  const int nb = (N + 255) / 256;

  // workspace layout
  float* ws = (float*)d_ws;
  float* xl = ws;                      // M
  float* xr = xl + (size_t)M;          // M
  int* deg = (int*)(xr + (size_t)M);   // N
  int* offs = deg + N;                 // N
  int* cursor = offs + N;              // N
  int* bsum = cursor + N;              // nb
  int2* csr = (int2*)((((size_t)(bsum + nb)) + 7) & ~(size_t)7);  // E int2
  double* red = (double*)((((size_t)(csr + E)) + 15) & ~(size_t)15);

  hipMemsetAsync(deg, 0, (size_t)N * 4, stream);
  hipMemsetAsync(cursor, 0, (size_t)N * 4, stream);
  hipMemsetAsync(red, 0, 16, stream);

  k_gemm_xlxr<<<(N + 31) / 32, 256, 0, stream>>>(x, Wl, bl, Wr, br, xl, xr, N);
  k_count<<<(E + 255) / 256, 256, 0, stream>>>(dstp, deg, E);
  k_scan1<<<nb, 256, 0, stream>>>(deg, bsum, N);
  k_scan2<<<1, 512, 0, stream>>>(bsum, nb);
  k_scan3<<<nb, 256, 0, stream>>>(deg, bsum, offs, N);
  k_fill<<<(E + 255) / 256, 256, 0, stream>>>(srcp, dstp, offs, cursor, csr, E);
  k_fused<<<2048, 256, 0, stream>>>(csr, offs, deg, edge_attr, xl, xr, We, att,
                                    x, bias, out, red, N);
  k_final<<<(M / 4 + 255) / 256, 256, 0, stream>>>(x, out, bias, red, lnw, lnb,
                                                   M / 4);
}

// Round 5
// 682.586 us; speedup vs baseline: 5.6286x; 1.1333x over previous
//
#include <hip/hip_runtime.h>
#include <hip/hip_bf16.h>

static constexpr float NEG_SLOPE = 0.2f;
static constexpr float LN_EPS = 1e-5f;

typedef float v2f __attribute__((ext_vector_type(2)));

// f32 -> bf16 (RNE) as ushort
__device__ __forceinline__ unsigned f2b(float f) {
  unsigned u = __float_as_uint(f);
  return (u + 0x7fffu + ((u >> 16) & 1u)) >> 16;
}
__device__ __forceinline__ float b2f(unsigned u) {
  return __uint_as_float(u << 16);
}
__device__ __forceinline__ v2f b2f2(ushort2 u) {
  v2f r;
  r.x = __uint_as_float((unsigned)u.x << 16);
  r.y = __uint_as_float((unsigned)u.y << 16);
  return r;
}

// ---- 16-lane (head-group) sum via DPP ----
__device__ __forceinline__ float head_sum16(float x) {
  float t;
  t = __int_as_float(__builtin_amdgcn_update_dpp(
      0, __float_as_int(x), 0xB1, 0xF, 0xF, true));  // quad_perm [1,0,3,2]
  x += t;
  t = __int_as_float(__builtin_amdgcn_update_dpp(
      0, __float_as_int(x), 0x4E, 0xF, 0xF, true));  // quad_perm [2,3,0,1]
  x += t;
  t = __int_as_float(__builtin_amdgcn_update_dpp(
      0, __float_as_int(x), 0x124, 0xF, 0xF, true));  // row_ror:4
  x += t;
  t = __int_as_float(__builtin_amdgcn_update_dpp(
      0, __float_as_int(x), 0x128, 0xF, 0xF, true));  // row_ror:8
  x += t;
  return x;
}

// ---- K1: xl = x@Wl + bl ; xr = x@Wr + br (bf16 outputs) ----
__global__ __launch_bounds__(256) void k_gemm_xlxr(
    const float* __restrict__ x, const float* __restrict__ Wl,
    const float* __restrict__ bl, const float* __restrict__ Wr,
    const float* __restrict__ br, ushort* __restrict__ xl,
    ushort* __restrict__ xr, int n)
{
  __shared__ float Xt[128 * 34];
  const int t = threadIdx.x;
  const int col = t & 127;
  const bool isR = t >= 128;
  const float* __restrict__ W = isR ? Wr : Wl;
  ushort* __restrict__ outp = isR ? xr : xl;
  const float bia = isR ? br[col] : bl[col];
  const int row0 = blockIdx.x * 32;
  const int nr = min(32, n - row0);
  for (int i = t; i < 32 * 128; i += 256) {
    int r = i >> 7, k = i & 127;
    Xt[k * 34 + r] = (r < nr) ? x[(row0 + r) * 128 + k] : 0.f;
  }
  __syncthreads();
  float acc[32];
#pragma unroll
  for (int r = 0; r < 32; ++r) acc[r] = 0.f;
#pragma unroll 4
  for (int k = 0; k < 128; ++k) {
    float w = W[k * 128 + col];
    const float2* xrow = (const float2*)(Xt + k * 34);
#pragma unroll
    for (int rr = 0; rr < 16; ++rr) {
      float2 xv = xrow[rr];
      acc[2 * rr] += xv.x * w;
      acc[2 * rr + 1] += xv.y * w;
    }
  }
  for (int r = 0; r < nr; ++r)
    outp[(size_t)(row0 + r) * 128 + col] = (ushort)f2b(acc[r] + bia);
}

// ---- K2: in-degree per dst ----
__global__ __launch_bounds__(256) void k_count(const int* __restrict__ dst,
                                               int* __restrict__ deg, int E)
{
  int e = blockIdx.x * 256 + threadIdx.x;
  if (e < E) atomicAdd(&deg[dst[e]], 1);
}

// ---- K3a/b/c: exclusive prefix scan of deg -> offs ----
__global__ __launch_bounds__(256) void k_scan1(const int* __restrict__ deg,
                                               int* __restrict__ bsum, int n)
{
  int i = blockIdx.x * 256 + threadIdx.x;
  int v = (i < n) ? deg[i] : 0;
#pragma unroll
  for (int o = 32; o > 0; o >>= 1) v += __shfl_down(v, o);
  __shared__ int ls[4];
  if ((threadIdx.x & 63) == 0) ls[threadIdx.x >> 6] = v;
  __syncthreads();
  if (threadIdx.x == 0) bsum[blockIdx.x] = ls[0] + ls[1] + ls[2] + ls[3];
}

__global__ __launch_bounds__(512) void k_scan2(int* __restrict__ bsum, int nb)
{
  __shared__ int s[512];
  int t = threadIdx.x;
  int v = (t < nb) ? bsum[t] : 0;
  s[t] = v;
  __syncthreads();
  for (int o = 1; o < 512; o <<= 1) {
    int u = (t >= o) ? s[t - o] : 0;
    __syncthreads();
    s[t] += u;
    __syncthreads();
  }
  if (t < nb) bsum[t] = s[t] - v;  // exclusive
}

__global__ __launch_bounds__(256) void k_scan3(const int* __restrict__ deg,
                                               const int* __restrict__ bsum,
                                               int* __restrict__ offs, int n)
{
  __shared__ int s[256];
  int b = blockIdx.x, t = threadIdx.x, i = b * 256 + t;
  int v = (i < n) ? deg[i] : 0;
  s[t] = v;
  __syncthreads();
  for (int o = 1; o < 256; o <<= 1) {
    int u = (t >= o) ? s[t - o] : 0;
    __syncthreads();
    s[t] += u;
    __syncthreads();
  }
  if (i < n) offs[i] = bsum[b] + s[t] - v;
}

// ---- K4: fill dst-CSR: src id + bf16 edge_attr permuted into CSR order ----
__global__ __launch_bounds__(256) void k_fill(
    const int* __restrict__ src, const int* __restrict__ dst,
    const int* __restrict__ offs, int* __restrict__ cursor,
    const float4* __restrict__ ea4, int* __restrict__ csr_src,
    ushort* __restrict__ csr_ea, int E)
{
  int e = blockIdx.x * 256 + threadIdx.x;
  if (e >= E) return;
  int d = dst[e];
  int pos = offs[d] + atomicAdd(&cursor[d], 1);
  csr_src[pos] = src[e];
  float4 r0 = ea4[(size_t)e * 4 + 0], r1 = ea4[(size_t)e * 4 + 1];
  float4 r2 = ea4[(size_t)e * 4 + 2], r3 = ea4[(size_t)e * 4 + 3];
  uint4* o4 = (uint4*)(csr_ea + (size_t)pos * 16);
  o4[0] = make_uint4(f2b(r0.x) | (f2b(r0.y) << 16), f2b(r0.z) | (f2b(r0.w) << 16),
                     f2b(r1.x) | (f2b(r1.y) << 16), f2b(r1.z) | (f2b(r1.w) << 16));
  o4[1] = make_uint4(f2b(r2.x) | (f2b(r2.y) << 16), f2b(r2.z) | (f2b(r2.w) << 16),
                     f2b(r3.x) | (f2b(r3.y) << 16), f2b(r3.z) | (f2b(r3.w) << 16));
}

// ---- K5: fused logits + online softmax + aggregation + LN-stat reduce ----
// One wave per node; lane j owns channels {2j,2j+1}; head = j>>4.
// Two softmax streams; (src,ea) prefetched 2-ahead, xl row 1-ahead.
__global__ __launch_bounds__(256) void k_fused(
    const int* __restrict__ csr_src, const ushort* __restrict__ csr_ea,
    const int* __restrict__ offs, const int* __restrict__ deg,
    const ushort* __restrict__ xl, const ushort* __restrict__ xr,
    const float* __restrict__ We, const float* __restrict__ att,
    const float* __restrict__ x, const float* __restrict__ bias,
    float* __restrict__ out, double* __restrict__ red, int N)
{
  const int lane = threadIdx.x & 63;
  const int gw = blockIdx.x * 4 + (threadIdx.x >> 6);
  const int nw = gridDim.x * 4;
  const v2f* __restrict__ We2 = (const v2f*)We;
  const v2f* __restrict__ X2 = (const v2f*)x;
  v2f* __restrict__ Out2 = (v2f*)out;

  v2f we[16];
#pragma unroll
  for (int k = 0; k < 16; ++k) we[k] = We2[k * 64 + lane];
  const v2f a2 = ((const v2f*)att)[lane];
  const v2f b2 = ((const v2f*)bias)[lane];

  float sred = 0.f, s2red = 0.f;

  for (int node = gw; node < N; node += nw) {
    const int beg = offs[node];
    const int len = deg[node];
    const v2f xrv = b2f2(*(const ushort2*)(xr + (size_t)node * 128 + 2 * lane));
    const v2f xvSelf =
        b2f2(*(const ushort2*)(xl + (size_t)node * 128 + 2 * lane));

    float mA = -1e30f, dA = 0.f, esA = 0.f;
    float mB = -1e30f, dB = 0.f, esB = 0.f;
    v2f aA = {0.f, 0.f}, aB = {0.f, 0.f};

    auto edge = [&](v2f xv, float eav, float& m, float& den, v2f& acc) {
      v2f emb = {0.f, 0.f};
#pragma unroll
      for (int k = 0; k < 16; ++k) {
        float eak = __int_as_float(
            __builtin_amdgcn_readlane(__float_as_int(eav), k));
        emb += eak * we[k];
      }
      v2f mm = xv + xrv + emb;
      v2f sl = mm * NEG_SLOPE;
      v2f ml;
      ml.x = fmaxf(mm.x, sl.x);
      ml.y = fmaxf(mm.y, sl.y);
      const float part = head_sum16(fmaf(ml.y, a2.y, ml.x * a2.x));
      const float mn = fmaxf(m, part);
      const float c = __expf(m - mn);
      const float p = __expf(part - mn);
      den = fmaf(den, c, p);
      acc = acc * c + xv * p;
      m = mn;
    };

    const int nB = len >> 1;
    const int nA = len - nB;  // A: [0,nA), B: [nA,len)
    const int lastA = beg + nA - 1;
    const int bB = beg + nA;
    const int lastB = beg + len - 1;

    int sA1 = 0, sB1 = 0;
    float eaA0 = 0.f, eaA1 = 0.f, eaB0 = 0.f, eaB1 = 0.f;
    v2f xvA0 = {0.f, 0.f}, xvB0 = {0.f, 0.f};

    if (len > 0) {
      int sA0 = csr_src[beg];
      eaA0 = (lane < 16) ? b2f(csr_ea[(size_t)beg * 16 + lane]) : 0.f;
      xvA0 = b2f2(*(const ushort2*)(xl + (size_t)sA0 * 128 + 2 * lane));
      int iA1 = min(beg + 1, lastA);
      sA1 = csr_src[iA1];
      eaA1 = (lane < 16) ? b2f(csr_ea[(size_t)iA1 * 16 + lane]) : 0.f;
    }
    if (nB > 0) {
      int sB0 = csr_src[bB];
      eaB0 = (lane < 16) ? b2f(csr_ea[(size_t)bB * 16 + lane]) : 0.f;
      xvB0 = b2f2(*(const ushort2*)(xl + (size_t)sB0 * 128 + 2 * lane));
      int iB1 = min(bB + 1, lastB);
      sB1 = csr_src[iB1];
      eaB1 = (lane < 16) ? b2f(csr_ea[(size_t)iB1 * 16 + lane]) : 0.f;
    }

    for (int i = 0; i < nB; ++i) {
      // issue loads for i+2 (src, ea) and i+1 (xl row)
      const int iA2 = min(beg + i + 2, lastA);
      const int iB2 = min(bB + i + 2, lastB);
      const int sA2 = csr_src[iA2];
      const int sB2 = csr_src[iB2];
      const float eaA2 =
          (lane < 16) ? b2f(csr_ea[(size_t)iA2 * 16 + lane]) : 0.f;
      const float eaB2 =
          (lane < 16) ? b2f(csr_ea[(size_t)iB2 * 16 + lane]) : 0.f;
      const v2f xvA1 =
          b2f2(*(const ushort2*)(xl + (size_t)sA1 * 128 + 2 * lane));
      const v2f xvB1 =
          b2f2(*(const ushort2*)(xl + (size_t)sB1 * 128 + 2 * lane));
      // process current edges
      esA += eaA0;
      esB += eaB0;
      edge(xvA0, eaA0, mA, dA, aA);
      edge(xvB0, eaB0, mB, dB, aB);
      // rotate pipeline
      sA1 = sA2;
      sB1 = sB2;
      eaA0 = eaA1;
      eaA1 = eaA2;
      eaB0 = eaB1;
      eaB1 = eaB2;
      xvA0 = xvA1;
      xvB0 = xvB1;
    }
    if (nA > nB) {  // odd tail on stream A (index nA-1)
      esA += eaA0;
      edge(xvA0, eaA0, mA, dA, aA);
    }
    // self loop: ea = mean of incoming edge_attr (0 if isolated)
    const float inv = (len > 0) ? 1.f / (float)len : 0.f;
    edge(xvSelf, (esA + esB) * inv, mA, dA, aA);

    // merge stream B into A
    const float mn = fmaxf(mA, mB);
    const float cA2 = __expf(mA - mn);
    const float cB2 = __expf(mB - mn);
    const float den = dA * cA2 + dB * cB2;
    const float invden = 1.f / den;
    const float o0 = (aA.x * cA2 + aB.x * cB2) * invden;
    const float o1 = (aA.y * cA2 + aB.y * cB2) * invden;
    Out2[(size_t)node * 64 + lane] = (v2f){o0, o1};

    // LN stats of z = x + o + bias
    const v2f xvn = X2[(size_t)node * 64 + lane];
    const float v0 = xvn.x + o0 + b2.x;
    const float v1 = xvn.y + o1 + b2.y;
    sred += v0 + v1;
    s2red += v0 * v0 + v1 * v1;
  }

  // block reduction of LN stats
#pragma unroll
  for (int o = 32; o > 0; o >>= 1) {
    sred += __shfl_down(sred, o);
    s2red += __shfl_down(s2red, o);
  }
  __shared__ double ls[4], ls2[4];
  const int w = threadIdx.x >> 6;
  if ((threadIdx.x & 63) == 0) {
    ls[w] = (double)sred;
    ls2[w] = (double)s2red;
  }
  __syncthreads();
  if (threadIdx.x == 0) {
    unsafeAtomicAdd(red, ls[0] + ls[1] + ls[2] + ls[3]);
    unsafeAtomicAdd(red + 1, ls2[0] + ls2[1] + ls2[2] + ls2[3]);
  }
}

// ---- K6: z = x+acc+bias, normalize, scale/shift, relu (in place on acc) ----
__global__ __launch_bounds__(256) void k_final(
    const float* __restrict__ x, float* __restrict__ acc,
    const float* __restrict__ bias, const double* __restrict__ red,
    const float* __restrict__ lnw, const float* __restrict__ lnb, int M4)
{
  int i = blockIdx.x * 256 + threadIdx.x;
  if (i >= M4) return;
  const double invM = 1.0 / ((double)M4 * 4.0);
  const double mu = red[0] * invM;
  const double var = red[1] * invM - mu * mu;
  const float sc = rsqrtf((float)var + LN_EPS);
  const float muf = (float)mu;
  const float4* X4 = (const float4*)x;
  const float4* B4 = (const float4*)bias;
  const float4* W4 = (const float4*)lnw;
  const float4* L4 = (const float4*)lnb;
  float4* A4 = (float4*)acc;
  float4 xv = X4[i], av = A4[i], bv = B4[i & 31], wv = W4[i & 31],
         lv = L4[i & 31];
  float4 o;
  o.x = fmaxf(((xv.x + av.x + bv.x) - muf) * sc * wv.x + lv.x, 0.f);
  o.y = fmaxf(((xv.y + av.y + bv.y) - muf) * sc * wv.y + lv.y, 0.f);
  o.z = fmaxf(((xv.z + av.z + bv.z) - muf) * sc * wv.z + lv.z, 0.f);
  o.w = fmaxf(((xv.w + av.w + bv.w) - muf) * sc * wv.w + lv.w, 0.f);
  A4[i] = o;
}

extern "C" void kernel_launch(void* const* d_in, const int* in_sizes, int n_in,
                              void* d_out, int out_size, void* d_ws,
                              size_t ws_size, hipStream_t stream)
{
  const float* x = (const float*)d_in[0];
  const int* ei = (const int*)d_in[1];
  const float* edge_attr = (const float*)d_in[2];
  const float* Wl = (const float*)d_in[3];
  const float* bl = (const float*)d_in[4];
  const float* Wr = (const float*)d_in[5];
  const float* br = (const float*)d_in[6];
  const float* We = (const float*)d_in[7];
  const float* att = (const float*)d_in[8];
  const float* bias = (const float*)d_in[9];
  const float* lnw = (const float*)d_in[10];
  const float* lnb = (const float*)d_in[11];
  float* out = (float*)d_out;

  const int N = in_sizes[0] / 128;
  const int E = in_sizes[1] / 2;
  const int M = N * 128;
  const int* srcp = ei;
  const int* dstp = ei + E;
  const int nb = (N + 255) / 256;

  // workspace layout (bf16 xl/xr + bf16 CSR-ordered edge_attr): ~110 MB
  ushort* xl = (ushort*)d_ws;                    // M ushort
  ushort* xr = xl + (size_t)M;                   // M ushort
  int* deg = (int*)(xr + (size_t)M);             // N
  int* offs = deg + N;                           // N
  int* cursor = offs + N;                        // N
  int* bsum = cursor + N;                        // nb
  int* csr_src = bsum + ((nb + 1) & ~1);         // E
  ushort* csr_ea =
      (ushort*)((((size_t)(csr_src + E)) + 31) & ~(size_t)31);  // E*16
  double* red =
      (double*)((((size_t)(csr_ea + (size_t)E * 16)) + 15) & ~(size_t)15);

  hipMemsetAsync(deg, 0, (size_t)N * 4, stream);
  hipMemsetAsync(cursor, 0, (size_t)N * 4, stream);
  hipMemsetAsync(red, 0, 16, stream);

  k_gemm_xlxr<<<(N + 31) / 32, 256, 0, stream>>>(x, Wl, bl, Wr, br, xl, xr, N);
  k_count<<<(E + 255) / 256, 256, 0, stream>>>(dstp, deg, E);
  k_scan1<<<nb, 256, 0, stream>>>(deg, bsum, N);
  k_scan2<<<1, 512, 0, stream>>>(bsum, nb);
  k_scan3<<<nb, 256, 0, stream>>>(deg, bsum, offs, N);
  k_fill<<<(E + 255) / 256, 256, 0, stream>>>(
      srcp, dstp, offs, cursor, (const float4*)edge_attr, csr_src, csr_ea, E);
  k_fused<<<2048, 256, 0, stream>>>(csr_src, csr_ea, offs, deg, xl, xr, We,
                                    att, x, bias, out, red, N);
  k_final<<<(M / 4 + 255) / 256, 256, 0, stream>>>(x, out, bias, red, lnw, lnb,
                                                   M / 4);
}

// Round 6
// 613.682 us; speedup vs baseline: 6.2605x; 1.1123x over previous
//
#include <hip/hip_runtime.h>
#include <hip/hip_bf16.h>

static constexpr float NEG_SLOPE = 0.2f;
static constexpr float LN_EPS = 1e-5f;

typedef float v2f __attribute__((ext_vector_type(2)));
typedef __attribute__((ext_vector_type(8))) short bf16x8;
typedef __attribute__((ext_vector_type(4))) float f32x4;

// f32 -> bf16 (RNE) as ushort
__device__ __forceinline__ unsigned f2b(float f) {
  unsigned u = __float_as_uint(f);
  return (u + 0x7fffu + ((u >> 16) & 1u)) >> 16;
}
__device__ __forceinline__ float b2f(unsigned u) {
  return __uint_as_float(u << 16);
}
__device__ __forceinline__ v2f b2f2(ushort2 u) {
  v2f r;
  r.x = __uint_as_float((unsigned)u.x << 16);
  r.y = __uint_as_float((unsigned)u.y << 16);
  return r;
}

// ---- 16-lane (head-group) sum via DPP ----
__device__ __forceinline__ float head_sum16(float x) {
  float t;
  t = __int_as_float(__builtin_amdgcn_update_dpp(
      0, __float_as_int(x), 0xB1, 0xF, 0xF, true));  // quad_perm [1,0,3,2]
  x += t;
  t = __int_as_float(__builtin_amdgcn_update_dpp(
      0, __float_as_int(x), 0x4E, 0xF, 0xF, true));  // quad_perm [2,3,0,1]
  x += t;
  t = __int_as_float(__builtin_amdgcn_update_dpp(
      0, __float_as_int(x), 0x124, 0xF, 0xF, true));  // row_ror:4
  x += t;
  t = __int_as_float(__builtin_amdgcn_update_dpp(
      0, __float_as_int(x), 0x128, 0xF, 0xF, true));  // row_ror:8
  x += t;
  return x;
}

// ---- K0: pack Wl|Wr into MFMA B-fragment order (bf16) + bias concat ----
// Bpack[t][s][lane][i] = Wcat[k = s*32 + (lane>>4)*8 + i][col = t*16 + (lane&15)]
__global__ __launch_bounds__(256) void k_packB(
    const float* __restrict__ Wl, const float* __restrict__ Wr,
    const float* __restrict__ bl, const float* __restrict__ br,
    ushort* __restrict__ Bpack, float* __restrict__ bcat)
{
  int tid = blockIdx.x * 256 + threadIdx.x;  // 0..4095
  int l = tid & 63, s = (tid >> 6) & 3, t = tid >> 8;
  int col = t * 16 + (l & 15);
  int kb = s * 32 + (l >> 4) * 8;
  const float* __restrict__ W = (col < 128) ? Wl : Wr;
  int c = col & 127;
  unsigned p[4];
#pragma unroll
  for (int i = 0; i < 4; ++i) {
    unsigned lo = f2b(W[(size_t)(kb + 2 * i) * 128 + c]);
    unsigned hi = f2b(W[(size_t)(kb + 2 * i + 1) * 128 + c]);
    p[i] = lo | (hi << 16);
  }
  *(uint4*)(Bpack + (size_t)tid * 8) = make_uint4(p[0], p[1], p[2], p[3]);
  if (tid < 256) bcat[tid] = (tid < 128) ? bl[tid] : br[tid - 128];
}

// ---- K1: xl|xr = x @ (Wl|Wr) + b via bf16 MFMA, bf16 outputs ----
// 4 waves/block, wave owns 16 rows x 256 cols (16 n-tiles), K=128 in 4 steps.
__global__ __launch_bounds__(256) void k_gemm_mfma(
    const float* __restrict__ x, const ushort* __restrict__ Bpack,
    const float* __restrict__ bcat, ushort* __restrict__ xl,
    ushort* __restrict__ xr, int n)
{
  const int lane = threadIdx.x & 63;
  const int w = threadIdx.x >> 6;
  const int row0 = blockIdx.x * 64 + w * 16;
  const int rowA = min(row0 + (lane & 15), n - 1);
  const int kgrp = lane >> 4;

  f32x4 acc[16];
#pragma unroll
  for (int t = 0; t < 16; ++t) acc[t] = (f32x4){0.f, 0.f, 0.f, 0.f};

#pragma unroll
  for (int s = 0; s < 4; ++s) {
    const float4* ap =
        (const float4*)(x + (size_t)rowA * 128 + s * 32 + kgrp * 8);
    float4 a0 = ap[0], a1 = ap[1];
    bf16x8 a;
    a[0] = (short)f2b(a0.x); a[1] = (short)f2b(a0.y);
    a[2] = (short)f2b(a0.z); a[3] = (short)f2b(a0.w);
    a[4] = (short)f2b(a1.x); a[5] = (short)f2b(a1.y);
    a[6] = (short)f2b(a1.z); a[7] = (short)f2b(a1.w);
#pragma unroll
    for (int t = 0; t < 16; ++t) {
      bf16x8 b =
          *(const bf16x8*)(Bpack + (((size_t)t * 4 + s) * 64 + lane) * 8);
      acc[t] = __builtin_amdgcn_mfma_f32_16x16x32_bf16(a, b, acc[t], 0, 0, 0);
    }
  }

  const int colg = lane & 15;
  const int rbase = row0 + (lane >> 4) * 4;
#pragma unroll
  for (int t = 0; t < 16; ++t) {
    const int col = t * 16 + colg;
    const float bia = bcat[col];
    ushort* __restrict__ outp = (col < 128) ? xl : xr;
    const int c = col & 127;
#pragma unroll
    for (int r = 0; r < 4; ++r) {
      const int R = rbase + r;
      if (R < n) outp[(size_t)R * 128 + c] = (ushort)f2b(acc[t][r] + bia);
    }
  }
}

// ---- K2: in-degree per dst ----
__global__ __launch_bounds__(256) void k_count(const int* __restrict__ dst,
                                               int* __restrict__ deg, int E)
{
  int e = blockIdx.x * 256 + threadIdx.x;
  if (e < E) atomicAdd(&deg[dst[e]], 1);
}

// ---- K3a/b/c: exclusive prefix scan of deg -> offs ----
__global__ __launch_bounds__(256) void k_scan1(const int* __restrict__ deg,
                                               int* __restrict__ bsum, int n)
{
  int i = blockIdx.x * 256 + threadIdx.x;
  int v = (i < n) ? deg[i] : 0;
#pragma unroll
  for (int o = 32; o > 0; o >>= 1) v += __shfl_down(v, o);
  __shared__ int ls[4];
  if ((threadIdx.x & 63) == 0) ls[threadIdx.x >> 6] = v;
  __syncthreads();
  if (threadIdx.x == 0) bsum[blockIdx.x] = ls[0] + ls[1] + ls[2] + ls[3];
}

__global__ __launch_bounds__(512) void k_scan2(int* __restrict__ bsum, int nb)
{
  __shared__ int s[512];
  int t = threadIdx.x;
  int v = (t < nb) ? bsum[t] : 0;
  s[t] = v;
  __syncthreads();
  for (int o = 1; o < 512; o <<= 1) {
    int u = (t >= o) ? s[t - o] : 0;
    __syncthreads();
    s[t] += u;
    __syncthreads();
  }
  if (t < nb) bsum[t] = s[t] - v;  // exclusive
}

__global__ __launch_bounds__(256) void k_scan3(const int* __restrict__ deg,
                                               const int* __restrict__ bsum,
                                               int* __restrict__ offs, int n)
{
  __shared__ int s[256];
  int b = blockIdx.x, t = threadIdx.x, i = b * 256 + t;
  int v = (i < n) ? deg[i] : 0;
  s[t] = v;
  __syncthreads();
  for (int o = 1; o < 256; o <<= 1) {
    int u = (t >= o) ? s[t - o] : 0;
    __syncthreads();
    s[t] += u;
    __syncthreads();
  }
  if (i < n) offs[i] = bsum[b] + s[t] - v;
}

// ---- K4: fill dst-CSR: src id + bf16 edge_attr permuted into CSR order ----
__global__ __launch_bounds__(256) void k_fill(
    const int* __restrict__ src, const int* __restrict__ dst,
    const int* __restrict__ offs, int* __restrict__ cursor,
    const float4* __restrict__ ea4, int* __restrict__ csr_src,
    ushort* __restrict__ csr_ea, int E)
{
  int e = blockIdx.x * 256 + threadIdx.x;
  if (e >= E) return;
  int d = dst[e];
  int pos = offs[d] + atomicAdd(&cursor[d], 1);
  csr_src[pos] = src[e];
  float4 r0 = ea4[(size_t)e * 4 + 0], r1 = ea4[(size_t)e * 4 + 1];
  float4 r2 = ea4[(size_t)e * 4 + 2], r3 = ea4[(size_t)e * 4 + 3];
  uint4* o4 = (uint4*)(csr_ea + (size_t)pos * 16);
  o4[0] = make_uint4(f2b(r0.x) | (f2b(r0.y) << 16), f2b(r0.z) | (f2b(r0.w) << 16),
                     f2b(r1.x) | (f2b(r1.y) << 16), f2b(r1.z) | (f2b(r1.w) << 16));
  o4[1] = make_uint4(f2b(r2.x) | (f2b(r2.y) << 16), f2b(r2.z) | (f2b(r2.w) << 16),
                     f2b(r3.x) | (f2b(r3.y) << 16), f2b(r3.z) | (f2b(r3.w) << 16));
}

// ---- K5: fused logits + online softmax + aggregation + LN-stat reduce ----
__global__ __launch_bounds__(256) void k_fused(
    const int* __restrict__ csr_src, const ushort* __restrict__ csr_ea,
    const int* __restrict__ offs, const int* __restrict__ deg,
    const ushort* __restrict__ xl, const ushort* __restrict__ xr,
    const float* __restrict__ We, const float* __restrict__ att,
    const float* __restrict__ x, const float* __restrict__ bias,
    float* __restrict__ out, double* __restrict__ red, int N)
{
  const int lane = threadIdx.x & 63;
  const int gw = blockIdx.x * 4 + (threadIdx.x >> 6);
  const int nw = gridDim.x * 4;
  const v2f* __restrict__ We2 = (const v2f*)We;
  const v2f* __restrict__ X2 = (const v2f*)x;
  v2f* __restrict__ Out2 = (v2f*)out;

  v2f we[16];
#pragma unroll
  for (int k = 0; k < 16; ++k) we[k] = We2[k * 64 + lane];
  const v2f a2 = ((const v2f*)att)[lane];
  const v2f b2 = ((const v2f*)bias)[lane];

  float sred = 0.f, s2red = 0.f;

  for (int node = gw; node < N; node += nw) {
    const int beg = offs[node];
    const int len = deg[node];
    const v2f xrv = b2f2(*(const ushort2*)(xr + (size_t)node * 128 + 2 * lane));
    const v2f xvSelf =
        b2f2(*(const ushort2*)(xl + (size_t)node * 128 + 2 * lane));

    float mA = -1e30f, dA = 0.f, esA = 0.f;
    float mB = -1e30f, dB = 0.f, esB = 0.f;
    v2f aA = {0.f, 0.f}, aB = {0.f, 0.f};

    auto edge = [&](v2f xv, float eav, float& m, float& den, v2f& acc) {
      v2f emb = {0.f, 0.f};
#pragma unroll
      for (int k = 0; k < 16; ++k) {
        float eak = __int_as_float(
            __builtin_amdgcn_readlane(__float_as_int(eav), k));
        emb += eak * we[k];
      }
      v2f mm = xv + xrv + emb;
      v2f sl = mm * NEG_SLOPE;
      v2f ml;
      ml.x = fmaxf(mm.x, sl.x);
      ml.y = fmaxf(mm.y, sl.y);
      const float part = head_sum16(fmaf(ml.y, a2.y, ml.x * a2.x));
      const float mn = fmaxf(m, part);
      const float c = __expf(m - mn);
      const float p = __expf(part - mn);
      den = fmaf(den, c, p);
      acc = acc * c + xv * p;
      m = mn;
    };

    const int nB = len >> 1;
    const int nA = len - nB;  // A: [0,nA), B: [nA,len)
    const int lastA = beg + nA - 1;
    const int bB = beg + nA;
    const int lastB = beg + len - 1;

    int sA1 = 0, sB1 = 0;
    float eaA0 = 0.f, eaA1 = 0.f, eaB0 = 0.f, eaB1 = 0.f;
    v2f xvA0 = {0.f, 0.f}, xvB0 = {0.f, 0.f};

    if (len > 0) {
      int sA0 = csr_src[beg];
      eaA0 = (lane < 16) ? b2f(csr_ea[(size_t)beg * 16 + lane]) : 0.f;
      xvA0 = b2f2(*(const ushort2*)(xl + (size_t)sA0 * 128 + 2 * lane));
      int iA1 = min(beg + 1, lastA);
      sA1 = csr_src[iA1];
      eaA1 = (lane < 16) ? b2f(csr_ea[(size_t)iA1 * 16 + lane]) : 0.f;
    }
    if (nB > 0) {
      int sB0 = csr_src[bB];
      eaB0 = (lane < 16) ? b2f(csr_ea[(size_t)bB * 16 + lane]) : 0.f;
      xvB0 = b2f2(*(const ushort2*)(xl + (size_t)sB0 * 128 + 2 * lane));
      int iB1 = min(bB + 1, lastB);
      sB1 = csr_src[iB1];
      eaB1 = (lane < 16) ? b2f(csr_ea[(size_t)iB1 * 16 + lane]) : 0.f;
    }

    for (int i = 0; i < nB; ++i) {
      const int iA2 = min(beg + i + 2, lastA);
      const int iB2 = min(bB + i + 2, lastB);
      const int sA2 = csr_src[iA2];
      const int sB2 = csr_src[iB2];
      const float eaA2 =
          (lane < 16) ? b2f(csr_ea[(size_t)iA2 * 16 + lane]) : 0.f;
      const float eaB2 =
          (lane < 16) ? b2f(csr_ea[(size_t)iB2 * 16 + lane]) : 0.f;
      const v2f xvA1 =
          b2f2(*(const ushort2*)(xl + (size_t)sA1 * 128 + 2 * lane));
      const v2f xvB1 =
          b2f2(*(const ushort2*)(xl + (size_t)sB1 * 128 + 2 * lane));
      esA += eaA0;
      esB += eaB0;
      edge(xvA0, eaA0, mA, dA, aA);
      edge(xvB0, eaB0, mB, dB, aB);
      sA1 = sA2;
      sB1 = sB2;
      eaA0 = eaA1;
      eaA1 = eaA2;
      eaB0 = eaB1;
      eaB1 = eaB2;
      xvA0 = xvA1;
      xvB0 = xvB1;
    }
    if (nA > nB) {
      esA += eaA0;
      edge(xvA0, eaA0, mA, dA, aA);
    }
    const float inv = (len > 0) ? 1.f / (float)len : 0.f;
    edge(xvSelf, (esA + esB) * inv, mA, dA, aA);

    const float mn = fmaxf(mA, mB);
    const float cA2 = __expf(mA - mn);
    const float cB2 = __expf(mB - mn);
    const float den = dA * cA2 + dB * cB2;
    const float invden = 1.f / den;
    const float o0 = (aA.x * cA2 + aB.x * cB2) * invden;
    const float o1 = (aA.y * cA2 + aB.y * cB2) * invden;
    Out2[(size_t)node * 64 + lane] = (v2f){o0, o1};

    const v2f xvn = X2[(size_t)node * 64 + lane];
    const float v0 = xvn.x + o0 + b2.x;
    const float v1 = xvn.y + o1 + b2.y;
    sred += v0 + v1;
    s2red += v0 * v0 + v1 * v1;
  }

#pragma unroll
  for (int o = 32; o > 0; o >>= 1) {
    sred += __shfl_down(sred, o);
    s2red += __shfl_down(s2red, o);
  }
  __shared__ double ls[4], ls2[4];
  const int w = threadIdx.x >> 6;
  if ((threadIdx.x & 63) == 0) {
    ls[w] = (double)sred;
    ls2[w] = (double)s2red;
  }
  __syncthreads();
  if (threadIdx.x == 0) {
    unsafeAtomicAdd(red, ls[0] + ls[1] + ls[2] + ls[3]);
    unsafeAtomicAdd(red + 1, ls2[0] + ls2[1] + ls2[2] + ls2[3]);
  }
}

// ---- K6: z = x+acc+bias, normalize, scale/shift, relu (in place on acc) ----
__global__ __launch_bounds__(256) void k_final(
    const float* __restrict__ x, float* __restrict__ acc,
    const float* __restrict__ bias, const double* __restrict__ red,
    const float* __restrict__ lnw, const float* __restrict__ lnb, int M4)
{
  int i = blockIdx.x * 256 + threadIdx.x;
  if (i >= M4) return;
  const double invM = 1.0 / ((double)M4 * 4.0);
  const double mu = red[0] * invM;
  const double var = red[1] * invM - mu * mu;
  const float sc = rsqrtf((float)var + LN_EPS);
  const float muf = (float)mu;
  const float4* X4 = (const float4*)x;
  const float4* B4 = (const float4*)bias;
  const float4* W4 = (const float4*)lnw;
  const float4* L4 = (const float4*)lnb;
  float4* A4 = (float4*)acc;
  float4 xv = X4[i], av = A4[i], bv = B4[i & 31], wv = W4[i & 31],
         lv = L4[i & 31];
  float4 o;
  o.x = fmaxf(((xv.x + av.x + bv.x) - muf) * sc * wv.x + lv.x, 0.f);
  o.y = fmaxf(((xv.y + av.y + bv.y) - muf) * sc * wv.y + lv.y, 0.f);
  o.z = fmaxf(((xv.z + av.z + bv.z) - muf) * sc * wv.z + lv.z, 0.f);
  o.w = fmaxf(((xv.w + av.w + bv.w) - muf) * sc * wv.w + lv.w, 0.f);
  A4[i] = o;
}

extern "C" void kernel_launch(void* const* d_in, const int* in_sizes, int n_in,
                              void* d_out, int out_size, void* d_ws,
                              size_t ws_size, hipStream_t stream)
{
  const float* x = (const float*)d_in[0];
  const int* ei = (const int*)d_in[1];
  const float* edge_attr = (const float*)d_in[2];
  const float* Wl = (const float*)d_in[3];
  const float* bl = (const float*)d_in[4];
  const float* Wr = (const float*)d_in[5];
  const float* br = (const float*)d_in[6];
  const float* We = (const float*)d_in[7];
  const float* att = (const float*)d_in[8];
  const float* bias = (const float*)d_in[9];
  const float* lnw = (const float*)d_in[10];
  const float* lnb = (const float*)d_in[11];
  float* out = (float*)d_out;

  const int N = in_sizes[0] / 128;
  const int E = in_sizes[1] / 2;
  const int M = N * 128;
  const int* srcp = ei;
  const int* dstp = ei + E;
  const int nb = (N + 255) / 256;

  // workspace layout (bf16 xl/xr + bf16 CSR-ordered edge_attr)
  ushort* xl = (ushort*)d_ws;                    // M ushort
  ushort* xr = xl + (size_t)M;                   // M ushort
  int* deg = (int*)(xr + (size_t)M);             // N
  int* offs = deg + N;                           // N
  int* cursor = offs + N;                        // N
  int* bsum = cursor + N;                        // nb
  int* csr_src = bsum + ((nb + 1) & ~1);         // E
  ushort* csr_ea =
      (ushort*)((((size_t)(csr_src + E)) + 31) & ~(size_t)31);  // E*16
  double* red =
      (double*)((((size_t)(csr_ea + (size_t)E * 16)) + 15) & ~(size_t)15);
  ushort* Bpack = (ushort*)(red + 2);            // 4096*8 ushort (64 KB)
  float* bcat = (float*)(Bpack + 4096 * 8);      // 256 floats

  hipMemsetAsync(deg, 0, (size_t)N * 4, stream);
  hipMemsetAsync(cursor, 0, (size_t)N * 4, stream);
  hipMemsetAsync(red, 0, 16, stream);

  k_packB<<<16, 256, 0, stream>>>(Wl, Wr, bl, br, Bpack, bcat);
  k_gemm_mfma<<<(N + 63) / 64, 256, 0, stream>>>(x, Bpack, bcat, xl, xr, N);
  k_count<<<(E + 255) / 256, 256, 0, stream>>>(dstp, deg, E);
  k_scan1<<<nb, 256, 0, stream>>>(deg, bsum, N);
  k_scan2<<<1, 512, 0, stream>>>(bsum, nb);
  k_scan3<<<nb, 256, 0, stream>>>(deg, bsum, offs, N);
  k_fill<<<(E + 255) / 256, 256, 0, stream>>>(
      srcp, dstp, offs, cursor, (const float4*)edge_attr, csr_src, csr_ea, E);
  k_fused<<<2048, 256, 0, stream>>>(csr_src, csr_ea, offs, deg, xl, xr, We,
                                    att, x, bias, out, red, N);
  k_final<<<(M / 4 + 255) / 256, 256, 0, stream>>>(x, out, bias, red, lnw, lnb,
                                                   M / 4);
}